// Round 11
// baseline (212.644 us; speedup 1.0000x reference)
//
#include <hip/hip_runtime.h>

#define H 360
#define W 720
#define NB 8
#define XC 3
#define YC 20
#define TX 240
#define TY 18
#define BPB (XC*YC)             // 60 blocks per batch
#define WR 34                   // window rows: gi = by-8+r
#define LST 260                 // LDS row stride (floats): 256 cols + 4 pad
#define DTS 600.0f
#define REARTH 6371000.0f
#define D2R 0.017453292519943295f

#define NQ1 (WR*64)             // 2176 preamble quads
#define NHALO 1096              // rows{0..7,26..33}x64 + rows 8..25 x quads{0,1,62,63}
#define NGROUPS 5               // 5 groups x 4 substeps = 20 steps
#define FLAG_STRIDE 32          // 128 B per flag line

// LLC-coherent 8B load/store (agent-scope relaxed atomic -> dwordx2 sc1)
static __device__ __forceinline__ float2 ldc8(const float* p) {
    unsigned long long u = __hip_atomic_load((const unsigned long long*)p,
                                             __ATOMIC_RELAXED, __HIP_MEMORY_SCOPE_AGENT);
    return __builtin_bit_cast(float2, u);
}
static __device__ __forceinline__ void stc8(float* p, float2 v) {
    __hip_atomic_store((unsigned long long*)p, __builtin_bit_cast(unsigned long long, v),
                       __ATOMIC_RELAXED, __HIP_MEMORY_SCOPE_AGENT);
}

__global__ __launch_bounds__(512, 4) void ocean_persist(
    const float* __restrict__ Tin, const float* __restrict__ ug,
    const float* __restrict__ vg, const float* __restrict__ lat,
    const float* __restrict__ lon, const float* __restrict__ mask,
    float* __restrict__ out, float* __restrict__ wsf, int* __restrict__ flags)
{
    __shared__ float sT[WR * LST];       // 35.4 KB -> 2 blocks/CU

    const int tid = threadIdx.x;
    const int b  = blockIdx.z;
    const int bx = blockIdx.x * TX;
    const int by = blockIdx.y * TY;
    const int plane = H * W;

    const float dlat = lat[1] - lat[0];               // -0.5
    const float dy   = REARTH * D2R * fabsf(dlat);
    const float sgn  = (dlat > 0.f) ? 1.f : -1.f;
    const float dlon = lon[1] - lon[0];
    const float i2dy = 0.5f / dy, i1dy = 1.f / dy;

    const float* Tb = Tin + b * plane;
    const float* ub = ug  + b * plane;
    const float* vb = vg  + b * plane;
    float* outb = out + b * plane;
    float* wsb  = wsf + b * plane;

    int* bflags = flags + b * BPB * FLAG_STRIDE;
    int* myflag = bflags + (blockIdx.y * XC + blockIdx.x) * FLAG_STRIDE;

    // ---------- strip mapping: wave = row-group ----------
    const int cq = tid & 63;             // col quad 0..63 (window cols 0..255)
    const int rg = tid >> 6;             // row group 0..7 (== wave id)
    const int c0 = cq << 2;
    const int a  = 1 + 4 * rg;           // first h row; rg owns h rows a..a+5
    const int gj0 = (bx - 8 + c0 + W) % W;
    const bool hlzb = (gj0 == 0);            // filter zero-pad left of gj=0
    const bool hrzb = (gj0 + 3 == W - 1);    // filter zero-pad right of gj=W-1
    const bool topB = (blockIdx.y == 0), botB = (blockIdx.y == YC - 1);

    // ---------- bake invariants ----------
    int goff1[5], lds1o[5];              // preamble quads
    #pragma unroll
    for (int k = 0; k < 5; ++k) {
        const int q = tid + 512 * k;
        if (q < NQ1) {
            const int r = q >> 6, cc0 = (q & 63) << 2;
            int gi = by - 8 + r; gi = min(max(gi, 0), H - 1);
            const int gj = (bx - 8 + cc0 + W) % W;
            goff1[k] = gi * W + gj;
            lds1o[k] = r * LST + cc0;
        } else goff1[k] = -1;
    }

    int hgo[3], hlo[3];                  // halo import quads (3/thread)
    #pragma unroll
    for (int t = 0; t < 3; ++t) {
        const int q = tid + 512 * t;
        if (q < NHALO) {
            int r, cc0;
            if (q < 1024) { const int ri = q >> 6; r = (ri < 8) ? ri : 18 + ri; cc0 = (q & 63) << 2; }
            else { const int u = q - 1024; r = 8 + (u >> 2); const int qi = u & 3;
                   cc0 = (qi < 2) ? (qi << 2) : (248 + ((qi - 2) << 2)); }
            int gi = by - 8 + r; gi = min(max(gi, 0), H - 1);
            const int gj = (bx - 8 + cc0 + W) % W;
            hgo[t] = gi * W + gj;
            hlo[t] = r * LST + cc0;
        } else hgo[t] = -1;
    }

    // advection coeffs for own 6 h rows (float4 loads; gj0 16B-aligned)
    float cuA[6][4], cvA[6][4];
    unsigned domm = 0;
    #pragma unroll
    for (int j = 0; j < 6; ++j) {
        #pragma unroll
        for (int t = 0; t < 4; ++t) { cuA[j][t] = 0.f; cvA[j][t] = 0.f; }
        const int hr = a + j;            // h row index in window
        const int gi = by - 8 + hr;
        if (hr <= 32 && (unsigned)gi < H) {
            const float dxv  = REARTH * D2R * dlon * cosf(lat[gi] * D2R);
            const float rdx2 = 0.5f / dxv;
            const float ivy  = (gi == 0 || gi == H - 1) ? i1dy : i2dy;
            const int base = gi * W + gj0;
            const float4 mk4 = *(const float4*)(mask + base);
            const float4 u4  = *(const float4*)(ub + base);
            const float4 v4  = *(const float4*)(vb + base);
            cuA[j][0] = -DTS * mk4.x * u4.x * rdx2;
            cuA[j][1] = -DTS * mk4.y * u4.y * rdx2;
            cuA[j][2] = -DTS * mk4.z * u4.z * rdx2;
            cuA[j][3] = -DTS * mk4.w * u4.w * rdx2;
            const float cs = sgn * ivy;
            cvA[j][0] = -DTS * mk4.x * v4.x * cs;
            cvA[j][1] = -DTS * mk4.y * v4.y * cs;
            cvA[j][2] = -DTS * mk4.z * v4.z * cs;
            cvA[j][3] = -DTS * mk4.w * v4.w * cs;
            domm |= 1u << j;
        }
    }

    // out rows n = 2+4rg+i, i = 0..3 (valid out rows are 2..31 only)
    float m16A[4][4];
    int o3A[4];
    unsigned outm = 0, tilem = 0;
    #pragma unroll
    for (int i = 0; i < 4; ++i) {
        const int n = 2 + 4 * rg + i;
        const int gi = by - 8 + n;
        o3A[i] = 0;
        #pragma unroll
        for (int t = 0; t < 4; ++t) m16A[i][t] = 0.f;
        if ((unsigned)gi < H) {
            const float4 mk4 = *(const float4*)(mask + gi * W + gj0);
            m16A[i][0] = mk4.x * (1.f / 16.f);
            m16A[i][1] = mk4.y * (1.f / 16.f);
            m16A[i][2] = mk4.z * (1.f / 16.f);
            m16A[i][3] = mk4.w * (1.f / 16.f);
            if (n <= 31) outm |= 1u << i;
        }
        const bool inTile = (n >= 8 && n <= 25 && cq >= 2 && cq <= 61);
        if (inTile) {
            o3A[i] = gi * W + bx + c0 - 8;
            tilem |= 1u << i;            // export = whole tile (ring ~= tile at TY=18)
        }
    }

    // neighbor flag pointers (8-neighborhood; x wraps mod XC, y clamps to self)
    const int* nbrF = myflag;
    if (tid < 8) {
        int dyn, dxn;
        if (tid < 3)      { dyn = -1; dxn = tid - 1; }
        else if (tid == 3){ dyn = 0;  dxn = -1; }
        else if (tid == 4){ dyn = 0;  dxn = 1; }
        else              { dyn = 1;  dxn = tid - 6; }
        const int ny = (int)blockIdx.y + dyn;
        const int nx = ((int)blockIdx.x + dxn + XC) % XC;
        if (ny >= 0 && ny < YC) nbrF = bflags + (ny * XC + nx) * FLAG_STRIDE;
    }

    // ---------- preamble: full window -> sT ----------
    #pragma unroll
    for (int k = 0; k < 5; ++k)
        if (goff1[k] >= 0)
            *(float4*)(sT + lds1o[k]) = *(const float4*)(Tb + goff1[k]);
    __syncthreads();

    // ---------- one substep: pure-register vertical pass ----------
    auto substep = [&](bool finalOut, float* ring) {
        float4 hA[6];
        float4 m1 = *(const float4*)(sT + (a - 1) * LST + c0);
        float4 cc = *(const float4*)(sT + a * LST + c0);
        #pragma unroll
        for (int j = 0; j < 6; ++j) {
            const int rD = min(a + j + 1, WR - 1);        // clamp: rg7 j=4,5 (unused hA)
            const float4 vD = *(const float4*)(sT + rD * LST + c0);
            const float tl = __shfl_up(cc.w, 1);    // garbage only at window col 0
            const float tr = __shfl_down(cc.x, 1);  // garbage only at window col 255
            const bool dj = (domm >> j) & 1;
            float4 o;
            o.x = (dj ? cc.x : 0.f) + cuA[j][0]*(cc.y - tl)   + cvA[j][0]*(vD.x - m1.x);
            o.y = (dj ? cc.y : 0.f) + cuA[j][1]*(cc.z - cc.x) + cvA[j][1]*(vD.y - m1.y);
            o.z = (dj ? cc.z : 0.f) + cuA[j][2]*(cc.w - cc.y) + cvA[j][2]*(vD.z - m1.z);
            o.w = (dj ? cc.w : 0.f) + cuA[j][3]*(tr   - cc.z) + cvA[j][3]*(vD.w - m1.w);
            float hl = __shfl_up(o.w, 1);
            float hr = __shfl_down(o.x, 1);
            if (hlzb) hl = 0.f;
            if (hrzb) hr = 0.f;
            hA[j].x = hl  + 2.f * o.x + o.y;
            hA[j].y = o.x + 2.f * o.y + o.z;
            hA[j].z = o.y + 2.f * o.z + o.w;
            hA[j].w = o.z + 2.f * o.w + hr;
            m1 = cc; cc = vD;
        }
        __syncthreads();     // all stage-2 reads done before any sT write
        #pragma unroll
        for (int i = 0; i < 4; ++i) {
            const float4 hm = hA[i], hc = hA[i + 1], hp = hA[i + 2];
            float4 o;
            o.x = (hm.x + 2.f * hc.x + hp.x) * m16A[i][0];
            o.y = (hm.y + 2.f * hc.y + hp.y) * m16A[i][1];
            o.z = (hm.z + 2.f * hc.z + hp.z) * m16A[i][2];
            o.w = (hm.w + 2.f * hc.w + hp.w) * m16A[i][3];
            if (!finalOut) {
                if ((outm >> i) & 1)
                    *(float4*)(sT + (2 + 4 * rg + i) * LST + c0) = o;
                // clamp-replica patches (edge rows are domain-suppressed above)
                if (topB && rg == 1 && i == 2) *(float4*)(sT + 7  * LST + c0) = o; // row7 <- n=8 (gi=0)
                if (botB && rg == 5 && i == 3) *(float4*)(sT + 26 * LST + c0) = o; // row26 <- n=25 (gi=H-1)
            } else if ((tilem >> i) & 1) {
                *(float4*)(outb + o3A[i]) = o;
            }
            if (ring && ((tilem >> i) & 1)) {
                float2 lo; lo.x = o.x; lo.y = o.y;
                float2 hi; hi.x = o.z; hi.y = o.w;
                stc8(ring + o3A[i], lo);
                stc8(ring + o3A[i] + 2, hi);
            }
        }
        __syncthreads();
    };

    // ---------- 5 groups x 4 substeps ----------
    #pragma unroll 1
    for (int g = 0; g < NGROUPS; ++g) {
        if (g) {
            __syncthreads();   // drains ring stores (per-wave vmcnt0 before s_barrier)
            if (tid == 0)
                __hip_atomic_store(myflag, g, __ATOMIC_RELAXED, __HIP_MEMORY_SCOPE_AGENT);
            if (tid < 64) {    // wave 0, lanes 0..7 poll the 8 neighbors
                long long t0 = (long long)clock64();
                for (;;) {
                    const int v = (tid < 8)
                        ? __hip_atomic_load(nbrF, __ATOMIC_RELAXED, __HIP_MEMORY_SCOPE_AGENT)
                        : 0x7fffffff;
                    if (__all(v >= g)) break;
                    __builtin_amdgcn_s_sleep(1);
                    if ((long long)clock64() - t0 > 200000000LL) break;  // no-hang bailout
                }
            }
            __syncthreads();
            // halo import (depth 8) from ring(g-1): g-1 even -> outb, odd -> wsb
            const float* prev = ((g - 1) & 1) ? wsb : outb;
            #pragma unroll
            for (int t = 0; t < 3; ++t) {
                if (hgo[t] >= 0) {
                    const float2 lo = ldc8(prev + hgo[t]);
                    const float2 hi = ldc8(prev + hgo[t] + 2);
                    float4 v; v.x = lo.x; v.y = lo.y; v.z = hi.x; v.w = hi.y;
                    *(float4*)(sT + hlo[t]) = v;
                }
            }
            __syncthreads();
        }
        const bool lastG = (g == NGROUPS - 1);
        float* ring = lastG ? nullptr : ((g & 1) ? wsb : outb);   // ring(g)
        substep(false, nullptr);
        substep(false, nullptr);
        substep(false, nullptr);
        substep(lastG, ring);            // 4th substep: export ring / final tile
    }
}

extern "C" void kernel_launch(void* const* d_in, const int* in_sizes, int n_in,
                              void* d_out, int out_size, void* d_ws, size_t ws_size,
                              hipStream_t stream)
{
    const float* T    = (const float*)d_in[0];
    const float* ug   = (const float*)d_in[1];
    const float* vg   = (const float*)d_in[2];
    const float* lat  = (const float*)d_in[3];
    const float* lon  = (const float*)d_in[4];
    const float* mask = (const float*)d_in[5];
    float* out = (float*)d_out;

    int*   flags = (int*)d_ws;                        // 8 x 60 flags @ 128 B
    float* wsf   = (float*)((char*)d_ws + 65536);     // odd-group ring buffer

    hipMemsetAsync(d_ws, 0, 65536, stream);

    ocean_persist<<<dim3(XC, YC, NB), dim3(512), 0, stream>>>(
        T, ug, vg, lat, lon, mask, out, wsf, flags);
}

// Round 12
// 150.227 us; speedup vs baseline: 1.4155x; 1.4155x over previous
//
#include <hip/hip_runtime.h>

#define H 360
#define W 720
#define NB 8
#define XC 3
#define YC 10
#define TX 240
#define TY 36
#define BPB (XC*YC)             // 30 blocks per batch
#define WR 52                   // window rows: gi = by-8+r, r in 0..51
#define LST 260                 // LDS row stride (floats): 256 cols + 4 pad
#define DTS 600.0f
#define REARTH 6371000.0f
#define D2R 0.017453292519943295f

#define NQ1 (WR*64)             // 3328 preamble quads
#define NHALO 1168              // rows{0..7,44..51}x64 + rows 8..43 x quads{0,1,62,63}
#define NGROUPS 5               // 5 groups x 4 substeps = 20 steps
#define FLAG_STRIDE 32          // 128 B per flag line

// LLC-coherent 8B load/store (agent-scope relaxed atomic -> dwordx2 sc1)
static __device__ __forceinline__ float2 ldc8(const float* p) {
    unsigned long long u = __hip_atomic_load((const unsigned long long*)p,
                                             __ATOMIC_RELAXED, __HIP_MEMORY_SCOPE_AGENT);
    return __builtin_bit_cast(float2, u);
}
static __device__ __forceinline__ void stc8(float* p, float2 v) {
    __hip_atomic_store((unsigned long long*)p, __builtin_bit_cast(unsigned long long, v),
                       __ATOMIC_RELAXED, __HIP_MEMORY_SCOPE_AGENT);
}

__global__ __launch_bounds__(1024, 4) void ocean_persist(
    const float* __restrict__ Tin, const float* __restrict__ ug,
    const float* __restrict__ vg, const float* __restrict__ lat,
    const float* __restrict__ lon, const float* __restrict__ mask,
    float* __restrict__ out, float* __restrict__ wsf, int* __restrict__ flags)
{
    __shared__ float sT[WR * LST];       // 54 KB; 1 block/CU

    const int tid = threadIdx.x;
    const int b  = blockIdx.z;
    const int bx = blockIdx.x * TX;
    const int by = blockIdx.y * TY;
    const int plane = H * W;

    const float dlat = lat[1] - lat[0];               // -0.5
    const float dy   = REARTH * D2R * fabsf(dlat);
    const float sgn  = (dlat > 0.f) ? 1.f : -1.f;
    const float dlon = lon[1] - lon[0];
    const float i2dy = 0.5f / dy, i1dy = 1.f / dy;

    const float* Tb = Tin + b * plane;
    const float* ub = ug  + b * plane;
    const float* vb = vg  + b * plane;
    float* outb = out + b * plane;
    float* wsb  = wsf + b * plane;

    int* bflags = flags + b * BPB * FLAG_STRIDE;
    int* myflag = bflags + (blockIdx.y * XC + blockIdx.x) * FLAG_STRIDE;

    // ---------- strip mapping: wave = row-group (16 groups x 64 lanes) ----------
    const int cq = tid & 63;             // col quad 0..63 (window cols 0..255)
    const int rg = tid >> 6;             // row group 0..15 (== wave id)
    const int c0 = cq << 2;
    const int a  = 1 + 3 * rg;           // first h row; rg owns h rows a..a+4 (max 50)
    const int gj0 = (bx - 8 + c0 + W) % W;
    const bool hlzb = (gj0 == 0);            // filter zero-pad left of gj=0
    const bool hrzb = (gj0 + 3 == W - 1);    // filter zero-pad right of gj=W-1
    const bool topB = (blockIdx.y == 0), botB = (blockIdx.y == YC - 1);

    // ---------- bake invariants ----------
    int goff1[4], lds1o[4];              // preamble quads
    #pragma unroll
    for (int k = 0; k < 4; ++k) {
        const int q = tid + 1024 * k;
        if (q < NQ1) {
            const int r = q >> 6, cc0 = (q & 63) << 2;
            int gi = by - 8 + r; gi = min(max(gi, 0), H - 1);
            const int gj = (bx - 8 + cc0 + W) % W;
            goff1[k] = gi * W + gj;
            lds1o[k] = r * LST + cc0;
        } else goff1[k] = -1;
    }

    int hgo[2], hlo[2];                  // halo import quads (2/thread)
    #pragma unroll
    for (int t = 0; t < 2; ++t) {
        const int q = tid + 1024 * t;
        if (q < NHALO) {
            int r, cc0;
            if (q < 1024) { const int ri = q >> 6; r = (ri < 8) ? ri : 36 + ri; cc0 = (q & 63) << 2; }
            else { const int u = q - 1024; r = 8 + (u >> 2); const int qi = u & 3;
                   cc0 = (qi < 2) ? (qi << 2) : (248 + ((qi - 2) << 2)); }
            int gi = by - 8 + r; gi = min(max(gi, 0), H - 1);
            const int gj = (bx - 8 + cc0 + W) % W;
            hgo[t] = gi * W + gj;
            hlo[t] = r * LST + cc0;
        } else hgo[t] = -1;
    }

    // advection coeffs for own 5 h rows (float4 loads; gj0 16B-aligned)
    float cuA[5][4], cvA[5][4];
    unsigned domm = 0;
    #pragma unroll
    for (int j = 0; j < 5; ++j) {
        #pragma unroll
        for (int t = 0; t < 4; ++t) { cuA[j][t] = 0.f; cvA[j][t] = 0.f; }
        const int gi = by - 8 + a + j;
        if ((unsigned)gi < H) {
            const float dxv  = REARTH * D2R * dlon * cosf(lat[gi] * D2R);
            const float rdx2 = 0.5f / dxv;
            const float ivy  = (gi == 0 || gi == H - 1) ? i1dy : i2dy;
            const int base = gi * W + gj0;
            const float4 mk4 = *(const float4*)(mask + base);
            const float4 u4  = *(const float4*)(ub + base);
            const float4 v4  = *(const float4*)(vb + base);
            cuA[j][0] = -DTS * mk4.x * u4.x * rdx2;
            cuA[j][1] = -DTS * mk4.y * u4.y * rdx2;
            cuA[j][2] = -DTS * mk4.z * u4.z * rdx2;
            cuA[j][3] = -DTS * mk4.w * u4.w * rdx2;
            const float cs = sgn * ivy;
            cvA[j][0] = -DTS * mk4.x * v4.x * cs;
            cvA[j][1] = -DTS * mk4.y * v4.y * cs;
            cvA[j][2] = -DTS * mk4.z * v4.z * cs;
            cvA[j][3] = -DTS * mk4.w * v4.w * cs;
            domm |= 1u << j;
        }
    }

    // out rows n = 2+3rg+i, i = 0..2 (n spans 2..49 exactly)
    float m16A[3][4];
    int o3A[3];
    unsigned outm = 0, tilem = 0, ringm = 0;
    #pragma unroll
    for (int i = 0; i < 3; ++i) {
        const int n = 2 + 3 * rg + i;
        const int gi = by - 8 + n;
        o3A[i] = 0;
        #pragma unroll
        for (int t = 0; t < 4; ++t) m16A[i][t] = 0.f;
        if ((unsigned)gi < H) {
            const float4 mk4 = *(const float4*)(mask + gi * W + gj0);
            m16A[i][0] = mk4.x * (1.f / 16.f);
            m16A[i][1] = mk4.y * (1.f / 16.f);
            m16A[i][2] = mk4.z * (1.f / 16.f);
            m16A[i][3] = mk4.w * (1.f / 16.f);
            outm |= 1u << i;
        }
        const bool inTile = (n >= 8 && n <= 43 && cq >= 2 && cq <= 61);
        if (inTile) {
            o3A[i] = gi * W + bx + c0 - 8;
            tilem |= 1u << i;
            if (n <= 15 || n >= 36 || cq <= 3 || cq >= 60) ringm |= 1u << i;
        }
    }

    // neighbor flag pointers (8-neighborhood; x wraps mod XC, y clamps to self)
    const int* nbrF = myflag;
    if (tid < 8) {
        int dyn, dxn;
        if (tid < 3)      { dyn = -1; dxn = tid - 1; }
        else if (tid == 3){ dyn = 0;  dxn = -1; }
        else if (tid == 4){ dyn = 0;  dxn = 1; }
        else              { dyn = 1;  dxn = tid - 6; }
        const int ny = (int)blockIdx.y + dyn;
        const int nx = ((int)blockIdx.x + dxn + XC) % XC;
        if (ny >= 0 && ny < YC) nbrF = bflags + (ny * XC + nx) * FLAG_STRIDE;
    }

    // ---------- preamble: full window -> sT ----------
    #pragma unroll
    for (int k = 0; k < 4; ++k)
        if (goff1[k] >= 0)
            *(float4*)(sT + lds1o[k]) = *(const float4*)(Tb + goff1[k]);
    __syncthreads();

    // ---------- one substep: pure-register vertical pass ----------
    auto substep = [&](bool finalOut, float* ring) {
        float4 hA[5];
        float4 m1 = *(const float4*)(sT + (a - 1) * LST + c0);
        float4 cc = *(const float4*)(sT + a * LST + c0);
        #pragma unroll
        for (int j = 0; j < 5; ++j) {
            const float4 vD = *(const float4*)(sT + (a + j + 1) * LST + c0);  // max row 51
            const float tl = __shfl_up(cc.w, 1);    // garbage only at window col 0
            const float tr = __shfl_down(cc.x, 1);  // garbage only at window col 255
            const bool dj = (domm >> j) & 1;
            float4 o;
            o.x = (dj ? cc.x : 0.f) + cuA[j][0]*(cc.y - tl)   + cvA[j][0]*(vD.x - m1.x);
            o.y = (dj ? cc.y : 0.f) + cuA[j][1]*(cc.z - cc.x) + cvA[j][1]*(vD.y - m1.y);
            o.z = (dj ? cc.z : 0.f) + cuA[j][2]*(cc.w - cc.y) + cvA[j][2]*(vD.z - m1.z);
            o.w = (dj ? cc.w : 0.f) + cuA[j][3]*(tr   - cc.z) + cvA[j][3]*(vD.w - m1.w);
            float hl = __shfl_up(o.w, 1);
            float hr = __shfl_down(o.x, 1);
            if (hlzb) hl = 0.f;
            if (hrzb) hr = 0.f;
            hA[j].x = hl  + 2.f * o.x + o.y;
            hA[j].y = o.x + 2.f * o.y + o.z;
            hA[j].z = o.y + 2.f * o.z + o.w;
            hA[j].w = o.z + 2.f * o.w + hr;
            m1 = cc; cc = vD;
        }
        __syncthreads();     // all stage-2 reads done before any sT write
        #pragma unroll
        for (int i = 0; i < 3; ++i) {
            const float4 hm = hA[i], hc = hA[i + 1], hp = hA[i + 2];
            float4 o;
            o.x = (hm.x + 2.f * hc.x + hp.x) * m16A[i][0];
            o.y = (hm.y + 2.f * hc.y + hp.y) * m16A[i][1];
            o.z = (hm.z + 2.f * hc.z + hp.z) * m16A[i][2];
            o.w = (hm.w + 2.f * hc.w + hp.w) * m16A[i][3];
            if (!finalOut) {
                if ((outm >> i) & 1)
                    *(float4*)(sT + (2 + 3 * rg + i) * LST + c0) = o;
                // clamp-replica patches (replica rows are domain-suppressed above)
                if (topB && rg == 2  && i == 0) *(float4*)(sT + 7  * LST + c0) = o; // row7  <- n=8  (gi=0)
                if (botB && rg == 13 && i == 2) *(float4*)(sT + 44 * LST + c0) = o; // row44 <- n=43 (gi=H-1)
            } else if ((tilem >> i) & 1) {
                *(float4*)(outb + o3A[i]) = o;
            }
            if (ring && ((ringm >> i) & 1)) {
                float2 lo; lo.x = o.x; lo.y = o.y;
                float2 hi; hi.x = o.z; hi.y = o.w;
                stc8(ring + o3A[i], lo);
                stc8(ring + o3A[i] + 2, hi);
            }
        }
        __syncthreads();
    };

    // ---------- 5 groups x 4 substeps ----------
    #pragma unroll 1
    for (int g = 0; g < NGROUPS; ++g) {
        if (g) {
            __syncthreads();   // drains ring stores (per-wave vmcnt0 before s_barrier)
            if (tid == 0)
                __hip_atomic_store(myflag, g, __ATOMIC_RELAXED, __HIP_MEMORY_SCOPE_AGENT);
            if (tid < 64) {    // wave 0, lanes 0..7 poll the 8 neighbors
                long long t0 = (long long)clock64();
                for (;;) {
                    const int v = (tid < 8)
                        ? __hip_atomic_load(nbrF, __ATOMIC_RELAXED, __HIP_MEMORY_SCOPE_AGENT)
                        : 0x7fffffff;
                    if (__all(v >= g)) break;
                    __builtin_amdgcn_s_sleep(1);
                    if ((long long)clock64() - t0 > 200000000LL) break;  // no-hang bailout
                }
            }
            __syncthreads();
            // halo import (depth 8) from ring(g-1): g-1 even -> outb, odd -> wsb
            const float* prev = ((g - 1) & 1) ? wsb : outb;
            #pragma unroll
            for (int t = 0; t < 2; ++t) {
                if (hgo[t] >= 0) {
                    const float2 lo = ldc8(prev + hgo[t]);
                    const float2 hi = ldc8(prev + hgo[t] + 2);
                    float4 v; v.x = lo.x; v.y = lo.y; v.z = hi.x; v.w = hi.y;
                    *(float4*)(sT + hlo[t]) = v;
                }
            }
            __syncthreads();
        }
        const bool lastG = (g == NGROUPS - 1);
        float* ring = lastG ? nullptr : ((g & 1) ? wsb : outb);   // ring(g)
        substep(false, nullptr);
        substep(false, nullptr);
        substep(false, nullptr);
        substep(lastG, ring);            // 4th substep: export ring / final tile
    }
}

extern "C" void kernel_launch(void* const* d_in, const int* in_sizes, int n_in,
                              void* d_out, int out_size, void* d_ws, size_t ws_size,
                              hipStream_t stream)
{
    const float* T    = (const float*)d_in[0];
    const float* ug   = (const float*)d_in[1];
    const float* vg   = (const float*)d_in[2];
    const float* lat  = (const float*)d_in[3];
    const float* lon  = (const float*)d_in[4];
    const float* mask = (const float*)d_in[5];
    float* out = (float*)d_out;

    int*   flags = (int*)d_ws;                        // 8 x 30 flags @ 128 B
    float* wsf   = (float*)((char*)d_ws + 65536);     // odd-group ring buffer

    hipMemsetAsync(d_ws, 0, 65536, stream);

    ocean_persist<<<dim3(XC, YC, NB), dim3(1024), 0, stream>>>(
        T, ug, vg, lat, lon, mask, out, wsf, flags);
}

// Round 13
// 150.034 us; speedup vs baseline: 1.4173x; 1.0013x over previous
//
#include <hip/hip_runtime.h>

#define H 360
#define W 720
#define NB 8
#define XC 3
#define YC 10
#define TX 240
#define TY 36
#define BPB (XC*YC)             // 30 blocks per batch
#define WR 52                   // window rows: gi = by-8+r, r in 0..51
#define LST 260                 // LDS row stride (floats): 256 cols + 4 pad
#define DTS 600.0f
#define REARTH 6371000.0f
#define D2R 0.017453292519943295f

#define NQ1 (WR*64)             // 3328 preamble quads
#define NHALO 1168              // rows{0..7,44..51}x64 + rows 8..43 x quads{0,1,62,63}
#define NGROUPS 5               // 5 groups x 4 substeps = 20 steps
#define FLAG_STRIDE 32          // 128 B per flag line

// LLC-coherent 8B load/store (agent-scope relaxed atomic -> dwordx2 sc1)
static __device__ __forceinline__ float2 ldc8(const float* p) {
    unsigned long long u = __hip_atomic_load((const unsigned long long*)p,
                                             __ATOMIC_RELAXED, __HIP_MEMORY_SCOPE_AGENT);
    return __builtin_bit_cast(float2, u);
}
static __device__ __forceinline__ void stc8(float* p, float2 v) {
    __hip_atomic_store((unsigned long long*)p, __builtin_bit_cast(unsigned long long, v),
                       __ATOMIC_RELAXED, __HIP_MEMORY_SCOPE_AGENT);
}

// NOTE launch bounds: empirically on gfx950 the 2nd arg N caps VGPRs at ~256/N
// (R9: N=2 -> 120 used; R10/R11: N=4 -> 64 -> scratch spill, +35 MB HBM).
// Working set here is ~95-120 VGPRs -> N=2 is the correct cap.
__global__ __launch_bounds__(1024, 2) void ocean_persist(
    const float* __restrict__ Tin, const float* __restrict__ ug,
    const float* __restrict__ vg, const float* __restrict__ lat,
    const float* __restrict__ lon, const float* __restrict__ mask,
    float* __restrict__ out, float* __restrict__ wsf, int* __restrict__ flags)
{
    __shared__ float sT[WR * LST];       // 54 KB; 1 block/CU

    const int tid = threadIdx.x;
    const int b  = blockIdx.z;
    const int bx = blockIdx.x * TX;
    const int by = blockIdx.y * TY;
    const int plane = H * W;

    const float dlat = lat[1] - lat[0];               // -0.5
    const float dy   = REARTH * D2R * fabsf(dlat);
    const float sgn  = (dlat > 0.f) ? 1.f : -1.f;
    const float dlon = lon[1] - lon[0];
    const float i2dy = 0.5f / dy, i1dy = 1.f / dy;

    const float* Tb = Tin + b * plane;
    const float* ub = ug  + b * plane;
    const float* vb = vg  + b * plane;
    float* outb = out + b * plane;
    float* wsb  = wsf + b * plane;

    int* bflags = flags + b * BPB * FLAG_STRIDE;
    int* myflag = bflags + (blockIdx.y * XC + blockIdx.x) * FLAG_STRIDE;

    // ---------- strip mapping: wave = row-group (16 groups x 64 lanes) ----------
    const int cq = tid & 63;             // col quad 0..63 (window cols 0..255)
    const int rg = tid >> 6;             // row group 0..15 (== wave id)
    const int c0 = cq << 2;
    const int a  = 1 + 3 * rg;           // first h row; rg owns h rows a..a+4 (max 50)
    const int gj0 = (bx - 8 + c0 + W) % W;
    const bool hlzb = (gj0 == 0);            // filter zero-pad left of gj=0
    const bool hrzb = (gj0 + 3 == W - 1);    // filter zero-pad right of gj=W-1
    const bool topB = (blockIdx.y == 0), botB = (blockIdx.y == YC - 1);

    // ---------- bake invariants ----------
    int goff1[4], lds1o[4];              // preamble quads
    #pragma unroll
    for (int k = 0; k < 4; ++k) {
        const int q = tid + 1024 * k;
        if (q < NQ1) {
            const int r = q >> 6, cc0 = (q & 63) << 2;
            int gi = by - 8 + r; gi = min(max(gi, 0), H - 1);
            const int gj = (bx - 8 + cc0 + W) % W;
            goff1[k] = gi * W + gj;
            lds1o[k] = r * LST + cc0;
        } else goff1[k] = -1;
    }

    int hgo[2], hlo[2];                  // halo import quads (2/thread)
    #pragma unroll
    for (int t = 0; t < 2; ++t) {
        const int q = tid + 1024 * t;
        if (q < NHALO) {
            int r, cc0;
            if (q < 1024) { const int ri = q >> 6; r = (ri < 8) ? ri : 36 + ri; cc0 = (q & 63) << 2; }
            else { const int u = q - 1024; r = 8 + (u >> 2); const int qi = u & 3;
                   cc0 = (qi < 2) ? (qi << 2) : (248 + ((qi - 2) << 2)); }
            int gi = by - 8 + r; gi = min(max(gi, 0), H - 1);
            const int gj = (bx - 8 + cc0 + W) % W;
            hgo[t] = gi * W + gj;
            hlo[t] = r * LST + cc0;
        } else hgo[t] = -1;
    }

    // advection coeffs for own 5 h rows (float4 loads; gj0 16B-aligned)
    float cuA[5][4], cvA[5][4];
    unsigned domm = 0;
    #pragma unroll
    for (int j = 0; j < 5; ++j) {
        #pragma unroll
        for (int t = 0; t < 4; ++t) { cuA[j][t] = 0.f; cvA[j][t] = 0.f; }
        const int gi = by - 8 + a + j;
        if ((unsigned)gi < H) {
            const float dxv  = REARTH * D2R * dlon * cosf(lat[gi] * D2R);
            const float rdx2 = 0.5f / dxv;
            const float ivy  = (gi == 0 || gi == H - 1) ? i1dy : i2dy;
            const int base = gi * W + gj0;
            const float4 mk4 = *(const float4*)(mask + base);
            const float4 u4  = *(const float4*)(ub + base);
            const float4 v4  = *(const float4*)(vb + base);
            cuA[j][0] = -DTS * mk4.x * u4.x * rdx2;
            cuA[j][1] = -DTS * mk4.y * u4.y * rdx2;
            cuA[j][2] = -DTS * mk4.z * u4.z * rdx2;
            cuA[j][3] = -DTS * mk4.w * u4.w * rdx2;
            const float cs = sgn * ivy;
            cvA[j][0] = -DTS * mk4.x * v4.x * cs;
            cvA[j][1] = -DTS * mk4.y * v4.y * cs;
            cvA[j][2] = -DTS * mk4.z * v4.z * cs;
            cvA[j][3] = -DTS * mk4.w * v4.w * cs;
            domm |= 1u << j;
        }
    }

    // out rows n = 2+3rg+i, i = 0..2 (n spans 2..49 exactly)
    float m16A[3][4];
    int o3A[3];
    unsigned outm = 0, tilem = 0, ringm = 0;
    #pragma unroll
    for (int i = 0; i < 3; ++i) {
        const int n = 2 + 3 * rg + i;
        const int gi = by - 8 + n;
        o3A[i] = 0;
        #pragma unroll
        for (int t = 0; t < 4; ++t) m16A[i][t] = 0.f;
        if ((unsigned)gi < H) {
            const float4 mk4 = *(const float4*)(mask + gi * W + gj0);
            m16A[i][0] = mk4.x * (1.f / 16.f);
            m16A[i][1] = mk4.y * (1.f / 16.f);
            m16A[i][2] = mk4.z * (1.f / 16.f);
            m16A[i][3] = mk4.w * (1.f / 16.f);
            outm |= 1u << i;
        }
        const bool inTile = (n >= 8 && n <= 43 && cq >= 2 && cq <= 61);
        if (inTile) {
            o3A[i] = gi * W + bx + c0 - 8;
            tilem |= 1u << i;
            if (n <= 15 || n >= 36 || cq <= 3 || cq >= 60) ringm |= 1u << i;
        }
    }

    // neighbor flag pointers (8-neighborhood; x wraps mod XC, y clamps to self)
    const int* nbrF = myflag;
    if (tid < 8) {
        int dyn, dxn;
        if (tid < 3)      { dyn = -1; dxn = tid - 1; }
        else if (tid == 3){ dyn = 0;  dxn = -1; }
        else if (tid == 4){ dyn = 0;  dxn = 1; }
        else              { dyn = 1;  dxn = tid - 6; }
        const int ny = (int)blockIdx.y + dyn;
        const int nx = ((int)blockIdx.x + dxn + XC) % XC;
        if (ny >= 0 && ny < YC) nbrF = bflags + (ny * XC + nx) * FLAG_STRIDE;
    }

    // ---------- preamble: full window -> sT ----------
    #pragma unroll
    for (int k = 0; k < 4; ++k)
        if (goff1[k] >= 0)
            *(float4*)(sT + lds1o[k]) = *(const float4*)(Tb + goff1[k]);
    __syncthreads();

    // ---------- one substep: pure-register vertical pass ----------
    auto substep = [&](bool finalOut, float* ring) {
        float4 hA[5];
        float4 m1 = *(const float4*)(sT + (a - 1) * LST + c0);
        float4 cc = *(const float4*)(sT + a * LST + c0);
        #pragma unroll
        for (int j = 0; j < 5; ++j) {
            const float4 vD = *(const float4*)(sT + (a + j + 1) * LST + c0);  // max row 51
            const float tl = __shfl_up(cc.w, 1);    // garbage only at window col 0
            const float tr = __shfl_down(cc.x, 1);  // garbage only at window col 255
            const bool dj = (domm >> j) & 1;
            float4 o;
            o.x = (dj ? cc.x : 0.f) + cuA[j][0]*(cc.y - tl)   + cvA[j][0]*(vD.x - m1.x);
            o.y = (dj ? cc.y : 0.f) + cuA[j][1]*(cc.z - cc.x) + cvA[j][1]*(vD.y - m1.y);
            o.z = (dj ? cc.z : 0.f) + cuA[j][2]*(cc.w - cc.y) + cvA[j][2]*(vD.z - m1.z);
            o.w = (dj ? cc.w : 0.f) + cuA[j][3]*(tr   - cc.z) + cvA[j][3]*(vD.w - m1.w);
            float hl = __shfl_up(o.w, 1);
            float hr = __shfl_down(o.x, 1);
            if (hlzb) hl = 0.f;
            if (hrzb) hr = 0.f;
            hA[j].x = hl  + 2.f * o.x + o.y;
            hA[j].y = o.x + 2.f * o.y + o.z;
            hA[j].z = o.y + 2.f * o.z + o.w;
            hA[j].w = o.z + 2.f * o.w + hr;
            m1 = cc; cc = vD;
        }
        __syncthreads();     // all stage-2 reads done before any sT write
        #pragma unroll
        for (int i = 0; i < 3; ++i) {
            const float4 hm = hA[i], hc = hA[i + 1], hp = hA[i + 2];
            float4 o;
            o.x = (hm.x + 2.f * hc.x + hp.x) * m16A[i][0];
            o.y = (hm.y + 2.f * hc.y + hp.y) * m16A[i][1];
            o.z = (hm.z + 2.f * hc.z + hp.z) * m16A[i][2];
            o.w = (hm.w + 2.f * hc.w + hp.w) * m16A[i][3];
            if (!finalOut) {
                if ((outm >> i) & 1)
                    *(float4*)(sT + (2 + 3 * rg + i) * LST + c0) = o;
                // clamp-replica patches (replica rows are domain-suppressed above)
                if (topB && rg == 2  && i == 0) *(float4*)(sT + 7  * LST + c0) = o; // row7  <- n=8  (gi=0)
                if (botB && rg == 13 && i == 2) *(float4*)(sT + 44 * LST + c0) = o; // row44 <- n=43 (gi=H-1)
            } else if ((tilem >> i) & 1) {
                *(float4*)(outb + o3A[i]) = o;
            }
            if (ring && ((ringm >> i) & 1)) {
                float2 lo; lo.x = o.x; lo.y = o.y;
                float2 hi; hi.x = o.z; hi.y = o.w;
                stc8(ring + o3A[i], lo);
                stc8(ring + o3A[i] + 2, hi);
            }
        }
        __syncthreads();
    };

    // ---------- 5 groups x 4 substeps ----------
    #pragma unroll 1
    for (int g = 0; g < NGROUPS; ++g) {
        if (g) {
            __syncthreads();   // drains ring stores (per-wave vmcnt0 before s_barrier)
            if (tid == 0)
                __hip_atomic_store(myflag, g, __ATOMIC_RELAXED, __HIP_MEMORY_SCOPE_AGENT);
            if (tid < 64) {    // wave 0, lanes 0..7 poll the 8 neighbors
                long long t0 = (long long)clock64();
                for (;;) {
                    const int v = (tid < 8)
                        ? __hip_atomic_load(nbrF, __ATOMIC_RELAXED, __HIP_MEMORY_SCOPE_AGENT)
                        : 0x7fffffff;
                    if (__all(v >= g)) break;
                    __builtin_amdgcn_s_sleep(1);
                    if ((long long)clock64() - t0 > 200000000LL) break;  // no-hang bailout
                }
            }
            __syncthreads();
            // halo import (depth 8) from ring(g-1): g-1 even -> outb, odd -> wsb
            const float* prev = ((g - 1) & 1) ? wsb : outb;
            #pragma unroll
            for (int t = 0; t < 2; ++t) {
                if (hgo[t] >= 0) {
                    const float2 lo = ldc8(prev + hgo[t]);
                    const float2 hi = ldc8(prev + hgo[t] + 2);
                    float4 v; v.x = lo.x; v.y = lo.y; v.z = hi.x; v.w = hi.y;
                    *(float4*)(sT + hlo[t]) = v;
                }
            }
            __syncthreads();
        }
        const bool lastG = (g == NGROUPS - 1);
        float* ring = lastG ? nullptr : ((g & 1) ? wsb : outb);   // ring(g)
        substep(false, nullptr);
        substep(false, nullptr);
        substep(false, nullptr);
        substep(lastG, ring);            // 4th substep: export ring / final tile
    }
}

extern "C" void kernel_launch(void* const* d_in, const int* in_sizes, int n_in,
                              void* d_out, int out_size, void* d_ws, size_t ws_size,
                              hipStream_t stream)
{
    const float* T    = (const float*)d_in[0];
    const float* ug   = (const float*)d_in[1];
    const float* vg   = (const float*)d_in[2];
    const float* lat  = (const float*)d_in[3];
    const float* lon  = (const float*)d_in[4];
    const float* mask = (const float*)d_in[5];
    float* out = (float*)d_out;

    int*   flags = (int*)d_ws;                        // 8 x 30 flags @ 128 B
    float* wsf   = (float*)((char*)d_ws + 65536);     // odd-group ring buffer

    hipMemsetAsync(d_ws, 0, 65536, stream);

    ocean_persist<<<dim3(XC, YC, NB), dim3(1024), 0, stream>>>(
        T, ug, vg, lat, lon, mask, out, wsf, flags);
}